// Round 1
// baseline (373.196 us; speedup 1.0000x reference)
//
#include <hip/hip_runtime.h>
#include <cfloat>
#include <cstddef>

// VQEmbeddingEMA inference forward.
// x:   [B=32, N*D=512, L=1024] f32
// emb: [N=8, M=512, D=64] f32
// out: quantized_st [B,512,L] (16777216 f32) ++ loss (1) ++ perplexity (1)

#define N_G   8
#define M_CB  512
#define D_DIM 64
#define B_SZ  32
#define L_SEQ 1024
#define TOKENS (N_G * B_SZ * L_SEQ)          // 262144
#define OUT_ELEMS ((size_t)B_SZ * N_G * D_DIM * L_SEQ)  // 16777216

// ws layout (4-byte units):
//   [0, 4096)    e2 table (float)       : ||e_nm||^2
//   [4096, 8192) counts (int)           : histogram per (n,m)
//   [8192]       loss accumulator (float)

__global__ void vq_e2_kernel(const float* __restrict__ emb, float* __restrict__ e2) {
    int i = blockIdx.x * blockDim.x + threadIdx.x;
    if (i < N_G * M_CB) {
        const float* e = emb + (size_t)i * D_DIM;
        float s0 = 0.f, s1 = 0.f, s2 = 0.f, s3 = 0.f;
        #pragma unroll
        for (int d = 0; d < D_DIM; d += 4) {
            s0 = fmaf(e[d+0], e[d+0], s0);
            s1 = fmaf(e[d+1], e[d+1], s1);
            s2 = fmaf(e[d+2], e[d+2], s2);
            s3 = fmaf(e[d+3], e[d+3], s3);
        }
        e2[i] = (s0 + s1) + (s2 + s3);
    }
}

__global__ __launch_bounds__(256, 4)
void vq_main_kernel(const float* __restrict__ x,
                    const float* __restrict__ emb,
                    const float* __restrict__ e2tab,
                    float* __restrict__ out,
                    int* __restrict__ counts,
                    float* __restrict__ lossAcc) {
    __shared__ int hist[M_CB];
    const int tid = threadIdx.x;
    hist[tid] = 0;
    hist[tid + 256] = 0;

    // block -> (n, b, l-tile). All block-uniform so codebook loads are scalar.
    const int bb  = blockIdx.x;          // [0, 1024)
    const int n   = bb >> 7;             // 128 blocks per group
    const int rem = bb & 127;
    const int b   = rem >> 2;            // 4 l-tiles per (n,b)
    const int l   = ((rem & 3) << 8) + tid;

    // x[b][n*64 + d][l], row stride L
    const size_t xbase = ((size_t)(b * N_G + n) * D_DIM) * L_SEQ + (size_t)l;

    float xv[D_DIM];
    #pragma unroll
    for (int d = 0; d < D_DIM; ++d)
        xv[d] = x[xbase + (size_t)d * L_SEQ];

    const float* __restrict__ eg  = emb + (size_t)n * (M_CB * D_DIM); // uniform
    const float* __restrict__ e2g = e2tab + n * M_CB;                 // uniform

    float best1 = FLT_MAX, best2 = FLT_MAX;
    int   idx1 = 0, idx2 = 0;

    #pragma unroll 2
    for (int m = 0; m < M_CB; ++m) {
        const float* __restrict__ em = eg + m * D_DIM; // wave-uniform address
        float a0 = 0.f, a1 = 0.f, a2 = 0.f, a3 = 0.f;
        #pragma unroll
        for (int d = 0; d < D_DIM; d += 4) {
            a0 = fmaf(xv[d+0], em[d+0], a0);
            a1 = fmaf(xv[d+1], em[d+1], a1);
            a2 = fmaf(xv[d+2], em[d+2], a2);
            a3 = fmaf(xv[d+3], em[d+3], a3);
        }
        const float dot  = (a0 + a1) + (a2 + a3);
        const float dist = fmaf(-2.f, dot, e2g[m]);   // x^2 const dropped: high precision

        const bool lt1 = dist < best1;
        const bool lt2 = dist < best2;
        const float nb2 = lt1 ? best1 : (lt2 ? dist : best2);
        const int   ni2 = lt1 ? idx1  : (lt2 ? m    : idx2);
        const float nb1 = lt1 ? dist : best1;
        const int   ni1 = lt1 ? m    : idx1;
        best2 = nb2; idx2 = ni2; best1 = nb1; idx1 = ni1;
    }

    // fp64 rescue for near-ties (expected ~2% of lanes; cheap: 2x64 fp64 FMA)
    if (best2 - best1 < 1e-4f) {
        const float* eA = eg + idx1 * D_DIM;
        const float* eB = eg + idx2 * D_DIM;
        double dA = 0.0, dB = 0.0;
        #pragma unroll
        for (int d = 0; d < D_DIM; ++d) {
            const double da = (double)xv[d] - (double)eA[d];
            const double db = (double)xv[d] - (double)eB[d];
            dA = fma(da, da, dA);
            dB = fma(db, db, dB);
        }
        if (dB < dA || (dB == dA && idx2 < idx1)) idx1 = idx2;
    }

    // epilogue: quantized write (straight-through value), loss partial, histogram
    const float* __restrict__ ebest = eg + (size_t)idx1 * D_DIM; // 256B aligned
    float sq = 0.f;
    #pragma unroll
    for (int d = 0; d < D_DIM; d += 4) {
        const float4 q = *reinterpret_cast<const float4*>(ebest + d);
        // mimic quantized_st = x + (q - x) in fp32 (== q up to 1 ulp)
        const float st0 = xv[d+0] + (q.x - xv[d+0]);
        const float st1 = xv[d+1] + (q.y - xv[d+1]);
        const float st2 = xv[d+2] + (q.z - xv[d+2]);
        const float st3 = xv[d+3] + (q.w - xv[d+3]);
        out[xbase + (size_t)(d+0) * L_SEQ] = st0;
        out[xbase + (size_t)(d+1) * L_SEQ] = st1;
        out[xbase + (size_t)(d+2) * L_SEQ] = st2;
        out[xbase + (size_t)(d+3) * L_SEQ] = st3;
        float f;
        f = xv[d+0] - q.x; sq = fmaf(f, f, sq);
        f = xv[d+1] - q.y; sq = fmaf(f, f, sq);
        f = xv[d+2] - q.z; sq = fmaf(f, f, sq);
        f = xv[d+3] - q.w; sq = fmaf(f, f, sq);
    }

    // wave-level loss reduction, one atomic per wave
    #pragma unroll
    for (int off = 32; off > 0; off >>= 1)
        sq += __shfl_down(sq, off, 64);
    if ((tid & 63) == 0)
        atomicAdd(lossAcc, sq);

    // per-block histogram -> global counts
    __syncthreads();
    atomicAdd(&hist[idx1], 1);
    __syncthreads();
    {
        const int base = n * M_CB;
        int c0 = hist[tid];
        int c1 = hist[tid + 256];
        if (c0) atomicAdd(&counts[base + tid], c0);
        if (c1) atomicAdd(&counts[base + tid + 256], c1);
    }
}

__global__ void vq_finalize_kernel(const int* __restrict__ counts,
                                   const float* __restrict__ lossAcc,
                                   float* __restrict__ outTail) {
    __shared__ float red[256];
    const int tid = threadIdx.x;
    float perp = 0.f;
    for (int n = 0; n < N_G; ++n) {
        float h = 0.f;
        for (int m = tid; m < M_CB; m += 256) {
            const float p = (float)counts[n * M_CB + m] * (1.0f / (B_SZ * L_SEQ));
            h += p * logf(p + 1e-10f);
        }
        red[tid] = h;
        __syncthreads();
        #pragma unroll
        for (int s = 128; s > 0; s >>= 1) {
            if (tid < s) red[tid] += red[tid + s];
            __syncthreads();
        }
        if (tid == 0) perp += expf(-red[0]);
        __syncthreads();
    }
    if (tid == 0) {
        outTail[0] = 0.25f * (lossAcc[0] / (float)OUT_ELEMS);  // commitment loss
        outTail[1] = perp;
    }
}

extern "C" void kernel_launch(void* const* d_in, const int* in_sizes, int n_in,
                              void* d_out, int out_size, void* d_ws, size_t ws_size,
                              hipStream_t stream) {
    const float* x   = (const float*)d_in[0];
    const float* emb = (const float*)d_in[1];
    float* out = (float*)d_out;

    float* e2tab   = (float*)d_ws;
    int*   counts  = (int*)((char*)d_ws + (size_t)N_G * M_CB * 4);
    float* lossAcc = (float*)((char*)d_ws + (size_t)2 * N_G * M_CB * 4);

    // zero counts + loss accumulator (harness does not re-poison between replays)
    hipMemsetAsync((char*)d_ws + (size_t)N_G * M_CB * 4, 0,
                   (size_t)N_G * M_CB * 4 + 4, stream);

    vq_e2_kernel<<<(N_G * M_CB + 255) / 256, 256, 0, stream>>>(emb, e2tab);
    vq_main_kernel<<<TOKENS / 256, 256, 0, stream>>>(x, emb, e2tab, out, counts, lossAcc);
    vq_finalize_kernel<<<1, 256, 0, stream>>>(counts, lossAcc, out + OUT_ELEMS);
}

// Round 2
// 134.260 us; speedup vs baseline: 2.7797x; 2.7797x over previous
//
#include <hip/hip_runtime.h>
#include <cfloat>
#include <cstddef>

// VQEmbeddingEMA inference forward — MFMA prescreen + exact fp32/fp64 rescore.
// x:   [B=32, N*D=512, L=1024] f32
// emb: [N=8, M=512, D=64] f32
// out: quantized_st [B,512,L] (16777216 f32) ++ loss (1) ++ perplexity (1)

#define N_G   8
#define M_CB  512
#define D_DIM 64
#define B_SZ  32
#define L_SEQ 1024
#define TOKENS (N_G * B_SZ * L_SEQ)                     // 262144
#define OUT_ELEMS ((size_t)B_SZ * N_G * D_DIM * L_SEQ)  // 16777216

typedef _Float16 f16x8 __attribute__((ext_vector_type(8)));
typedef float    f32x4 __attribute__((ext_vector_type(4)));

// ---------------- workspace layout (MFMA path) ----------------
//   [0,       524288)  e_f16  : codebook as f16, [n][m][d]
//   [524288,  540672)  e2p    : 1.0f + ||e||^2   (packed-prescreen table)
//   [540672,  557056)  e2raw  : ||e||^2          (exact fp32 rescore table)
//   [557056,  573440)  counts : int histogram [n][m]
//   [573440,  573444)  lossAcc: float
#define EF_OFF   0
#define E2P_OFF  524288
#define E2R_OFF  540672
#define CNT_OFF  557056
#define LOSS_OFF 573440
#define WS_NEEDED 573444

__global__ void vq_ef16_kernel(const float* __restrict__ emb, unsigned int* __restrict__ ef) {
    int i = blockIdx.x * blockDim.x + threadIdx.x;    // handles 2 elements
    if (i < N_G * M_CB * D_DIM / 2) {
        float2 v = reinterpret_cast<const float2*>(emb)[i];
        _Float16 h0 = (_Float16)v.x;
        _Float16 h1 = (_Float16)v.y;
        unsigned int u0 = (unsigned int)__builtin_bit_cast(unsigned short, h0);
        unsigned int u1 = (unsigned int)__builtin_bit_cast(unsigned short, h1);
        ef[i] = u0 | (u1 << 16);
    }
}

__global__ void vq_e2_kernel(const float* __restrict__ emb,
                             float* __restrict__ e2raw,
                             float* __restrict__ e2p) {
    int i = blockIdx.x * blockDim.x + threadIdx.x;
    if (i < N_G * M_CB) {
        const float* e = emb + (size_t)i * D_DIM;
        float s0 = 0.f, s1 = 0.f, s2 = 0.f, s3 = 0.f;
        #pragma unroll
        for (int d = 0; d < D_DIM; d += 4) {
            s0 = fmaf(e[d+0], e[d+0], s0);
            s1 = fmaf(e[d+1], e[d+1], s1);
            s2 = fmaf(e[d+2], e[d+2], s2);
            s3 = fmaf(e[d+3], e[d+3], s3);
        }
        float s = (s0 + s1) + (s2 + s3);
        e2raw[i] = s;
        if (e2p) e2p[i] = 1.0f + s;
    }
}

// ---------------- MFMA main kernel ----------------
// Block = 256 thr = 4 waves, 256 tokens (one (n,b) pair, 256 consecutive l).
// Wave = 64 consecutive l, as 4 strips of 16 tokens.
// Per strip: D[m-tile 16][tok 16] = mfma(A=E[16m][32k], B=X[32k][16tok]) x2 k-chunks.
__global__ __launch_bounds__(256, 4)
void vq_mfma_kernel(const float* __restrict__ x,
                    const float* __restrict__ emb,
                    const unsigned short* __restrict__ ef16,
                    const float* __restrict__ e2raw,
                    const float* __restrict__ e2p,
                    float* __restrict__ out,
                    int* __restrict__ counts,
                    float* __restrict__ lossAcc) {
    __shared__ int hist[M_CB];
    __shared__ int cands[4][4][16][8];   // [wave][strip][col][4 lane-slots x top2]

    const int tid  = threadIdx.x;
    hist[tid] = 0;
    hist[tid + 256] = 0;

    const int lane = tid & 63;
    const int wv   = tid >> 6;
    const int cc   = lane & 15;          // token col within strip / A-row (m)
    const int kl   = lane >> 4;          // k-chunk id / D row-group
    const int kl4  = kl * 4;

    const int bb  = blockIdx.x;          // [0,1024)
    const int n   = bb >> 7;
    const int rem = bb & 127;
    const int b   = rem >> 2;
    const int l0  = ((rem & 3) << 8) + (wv << 6);   // wave's token base

    const float* __restrict__ xg = x + (size_t)(b * N_G + n) * D_DIM * L_SEQ;
    const unsigned short* __restrict__ eg16 = ef16 + (size_t)n * M_CB * D_DIM;
    const float* __restrict__ e2pg = e2p + n * M_CB;

    // ---- load X fragments (direct from global, convert to f16) ----
    f16x8 xf[4][2];
    #pragma unroll
    for (int s = 0; s < 4; ++s) {
        const int tok = l0 + s * 16 + cc;
        #pragma unroll
        for (int kc = 0; kc < 2; ++kc) {
            const int dbase = kc * 32 + kl * 8;
            f16x8 v;
            #pragma unroll
            for (int j = 0; j < 8; ++j)
                v[j] = (_Float16)xg[(size_t)(dbase + j) * L_SEQ + tok];
            xf[s][kc] = v;
        }
    }

    int t1[4], t2[4];
    #pragma unroll
    for (int s = 0; s < 4; ++s) { t1[s] = 0x7FFFFFFF; t2[s] = 0x7FFFFFFF; }

    const f32x4 zero4 = {0.f, 0.f, 0.f, 0.f};

    // ---- prescreen: 32 m-tiles ----
    #pragma unroll 2
    for (int mt = 0; mt < 32; ++mt) {
        const unsigned short* erow = eg16 + (size_t)(mt * 16 + cc) * D_DIM + kl * 8;
        const f16x8 ea0 = *reinterpret_cast<const f16x8*>(erow);
        const f16x8 ea1 = *reinterpret_cast<const f16x8*>(erow + 32);
        const f32x4 e2v = *reinterpret_cast<const f32x4*>(e2pg + mt * 16 + kl4);
        const int mb = mt * 16 + kl4;    // m base for this lane's D rows

        #pragma unroll
        for (int s = 0; s < 4; ++s) {
            f32x4 dacc = __builtin_amdgcn_mfma_f32_16x16x32_f16(ea0, xf[s][0], zero4, 0, 0, 0);
            dacc       = __builtin_amdgcn_mfma_f32_16x16x32_f16(ea1, xf[s][1], dacc,  0, 0, 0);
            #pragma unroll
            for (int r = 0; r < 4; ++r) {
                // qf = 1 + e2 - 2*dot  in (0.5, 1.5): positive -> int-monotone
                const float qf = fmaf(dacc[r], -2.0f, e2v[r]);
                const int   pv = (__float_as_int(qf) & ~511) + (mb + r);
                const int   mx = max(t1[s], pv);
                t1[s] = min(t1[s], pv);
                t2[s] = min(t2[s], mx);
            }
        }
    }

    // ---- hand candidates to owning lane via LDS ----
    #pragma unroll
    for (int s = 0; s < 4; ++s) {
        cands[wv][s][cc][kl * 2 + 0] = t1[s];
        cands[wv][s][cc][kl * 2 + 1] = t2[s];
    }
    __syncthreads();

    const int tok = l0 + lane;           // lane owns token: strip = kl, col = cc
    int cd[8];
    #pragma unroll
    for (int j = 0; j < 8; ++j) cd[j] = cands[wv][kl][cc][j];
    int pmin = cd[0];
    #pragma unroll
    for (int j = 1; j < 8; ++j) pmin = min(pmin, cd[j]);

    // ---- reload this token's x column (fp32, coalesced, L2-hot) ----
    float xv[D_DIM];
    #pragma unroll
    for (int d = 0; d < D_DIM; ++d)
        xv[d] = xg[(size_t)d * L_SEQ + tok];

    // ---- exact fp32 rescore of near-minimal candidates ----
    const float* __restrict__ eg  = emb + (size_t)n * M_CB * D_DIM;
    const float* __restrict__ e2g = e2raw + n * M_CB;
    float best1 = FLT_MAX, best2 = FLT_MAX;
    int   idx1  = 0x7FFFFFFF, idx2 = 0x7FFFFFFF;
    for (int j = 0; j < 8; ++j) {
        if (cd[j] - pmin <= 2560) {      // covers f16 + quantization error margin
            const int m = cd[j] & 511;
            const float4* em4 = reinterpret_cast<const float4*>(eg + (size_t)m * D_DIM);
            float a0 = 0.f, a1 = 0.f, a2 = 0.f, a3 = 0.f;
            #pragma unroll
            for (int q = 0; q < 16; ++q) {
                const float4 e4 = em4[q];
                a0 = fmaf(xv[q*4+0], e4.x, a0);
                a1 = fmaf(xv[q*4+1], e4.y, a1);
                a2 = fmaf(xv[q*4+2], e4.z, a2);
                a3 = fmaf(xv[q*4+3], e4.w, a3);
            }
            const float dist = fmaf(-2.f, (a0 + a1) + (a2 + a3), e2g[m]);
            if (dist < best1 || (dist == best1 && m < idx1)) {
                best2 = best1; idx2 = idx1; best1 = dist; idx1 = m;
            } else if (dist < best2 || (dist == best2 && m < idx2)) {
                best2 = dist; idx2 = m;
            }
        }
    }

    // ---- fp64 rescue for near-ties (same semantics as validated R1 kernel) ----
    if (best2 - best1 < 1e-4f) {
        const float* eA = eg + (size_t)idx1 * D_DIM;
        const float* eB = eg + (size_t)idx2 * D_DIM;
        double dA = 0.0, dB = 0.0;
        #pragma unroll
        for (int d = 0; d < D_DIM; ++d) {
            const double da = (double)xv[d] - (double)eA[d];
            const double db = (double)xv[d] - (double)eB[d];
            dA = fma(da, da, dA);
            dB = fma(db, db, dB);
        }
        if (dB < dA || (dB == dA && idx2 < idx1)) idx1 = idx2;
    }

    // ---- epilogue: quantized write, loss partial, histogram ----
    const size_t obase = (size_t)(b * N_G + n) * D_DIM * L_SEQ + (size_t)tok;
    const float* __restrict__ ebest = eg + (size_t)idx1 * D_DIM;
    float sq = 0.f;
    #pragma unroll
    for (int d = 0; d < D_DIM; d += 4) {
        const float4 qv = *reinterpret_cast<const float4*>(ebest + d);
        out[obase + (size_t)(d+0) * L_SEQ] = xv[d+0] + (qv.x - xv[d+0]);
        out[obase + (size_t)(d+1) * L_SEQ] = xv[d+1] + (qv.y - xv[d+1]);
        out[obase + (size_t)(d+2) * L_SEQ] = xv[d+2] + (qv.z - xv[d+2]);
        out[obase + (size_t)(d+3) * L_SEQ] = xv[d+3] + (qv.w - xv[d+3]);
        float f;
        f = xv[d+0] - qv.x; sq = fmaf(f, f, sq);
        f = xv[d+1] - qv.y; sq = fmaf(f, f, sq);
        f = xv[d+2] - qv.z; sq = fmaf(f, f, sq);
        f = xv[d+3] - qv.w; sq = fmaf(f, f, sq);
    }

    #pragma unroll
    for (int off = 32; off > 0; off >>= 1)
        sq += __shfl_down(sq, off, 64);
    if (lane == 0)
        atomicAdd(lossAcc, sq);

    atomicAdd(&hist[idx1], 1);
    __syncthreads();
    {
        const int base = n * M_CB;
        int c0 = hist[tid];
        int c1 = hist[tid + 256];
        if (c0) atomicAdd(&counts[base + tid], c0);
        if (c1) atomicAdd(&counts[base + tid + 256], c1);
    }
}

// ---------------- fallback (validated R1 path, used if ws too small) ----------------
__global__ __launch_bounds__(256, 4)
void vq_main_fallback(const float* __restrict__ x,
                      const float* __restrict__ emb,
                      const float* __restrict__ e2tab,
                      float* __restrict__ out,
                      int* __restrict__ counts,
                      float* __restrict__ lossAcc) {
    __shared__ int hist[M_CB];
    const int tid = threadIdx.x;
    hist[tid] = 0;
    hist[tid + 256] = 0;

    const int bb  = blockIdx.x;
    const int n   = bb >> 7;
    const int rem = bb & 127;
    const int b   = rem >> 2;
    const int l   = ((rem & 3) << 8) + tid;

    const size_t xbase = ((size_t)(b * N_G + n) * D_DIM) * L_SEQ + (size_t)l;

    float xv[D_DIM];
    #pragma unroll
    for (int d = 0; d < D_DIM; ++d)
        xv[d] = x[xbase + (size_t)d * L_SEQ];

    const float* __restrict__ eg  = emb + (size_t)n * (M_CB * D_DIM);
    const float* __restrict__ e2g = e2tab + n * M_CB;

    float best1 = FLT_MAX, best2 = FLT_MAX;
    int   idx1 = 0, idx2 = 0;

    #pragma unroll 2
    for (int m = 0; m < M_CB; ++m) {
        const float* __restrict__ em = eg + m * D_DIM;
        float a0 = 0.f, a1 = 0.f, a2 = 0.f, a3 = 0.f;
        #pragma unroll
        for (int d = 0; d < D_DIM; d += 4) {
            a0 = fmaf(xv[d+0], em[d+0], a0);
            a1 = fmaf(xv[d+1], em[d+1], a1);
            a2 = fmaf(xv[d+2], em[d+2], a2);
            a3 = fmaf(xv[d+3], em[d+3], a3);
        }
        const float dot  = (a0 + a1) + (a2 + a3);
        const float dist = fmaf(-2.f, dot, e2g[m]);
        const bool lt1 = dist < best1;
        const bool lt2 = dist < best2;
        const float nb2 = lt1 ? best1 : (lt2 ? dist : best2);
        const int   ni2 = lt1 ? idx1  : (lt2 ? m    : idx2);
        const float nb1 = lt1 ? dist : best1;
        const int   ni1 = lt1 ? m    : idx1;
        best2 = nb2; idx2 = ni2; best1 = nb1; idx1 = ni1;
    }

    if (best2 - best1 < 1e-4f) {
        const float* eA = eg + idx1 * D_DIM;
        const float* eB = eg + idx2 * D_DIM;
        double dA = 0.0, dB = 0.0;
        #pragma unroll
        for (int d = 0; d < D_DIM; ++d) {
            const double da = (double)xv[d] - (double)eA[d];
            const double db = (double)xv[d] - (double)eB[d];
            dA = fma(da, da, dA);
            dB = fma(db, db, dB);
        }
        if (dB < dA || (dB == dA && idx2 < idx1)) idx1 = idx2;
    }

    const float* __restrict__ ebest = eg + (size_t)idx1 * D_DIM;
    float sq = 0.f;
    #pragma unroll
    for (int d = 0; d < D_DIM; d += 4) {
        const float4 q = *reinterpret_cast<const float4*>(ebest + d);
        out[xbase + (size_t)(d+0) * L_SEQ] = xv[d+0] + (q.x - xv[d+0]);
        out[xbase + (size_t)(d+1) * L_SEQ] = xv[d+1] + (q.y - xv[d+1]);
        out[xbase + (size_t)(d+2) * L_SEQ] = xv[d+2] + (q.z - xv[d+2]);
        out[xbase + (size_t)(d+3) * L_SEQ] = xv[d+3] + (q.w - xv[d+3]);
        float f;
        f = xv[d+0] - q.x; sq = fmaf(f, f, sq);
        f = xv[d+1] - q.y; sq = fmaf(f, f, sq);
        f = xv[d+2] - q.z; sq = fmaf(f, f, sq);
        f = xv[d+3] - q.w; sq = fmaf(f, f, sq);
    }
    #pragma unroll
    for (int off = 32; off > 0; off >>= 1)
        sq += __shfl_down(sq, off, 64);
    if ((tid & 63) == 0)
        atomicAdd(lossAcc, sq);

    __syncthreads();
    atomicAdd(&hist[idx1], 1);
    __syncthreads();
    {
        const int base = n * M_CB;
        int c0 = hist[tid];
        int c1 = hist[tid + 256];
        if (c0) atomicAdd(&counts[base + tid], c0);
        if (c1) atomicAdd(&counts[base + tid + 256], c1);
    }
}

__global__ void vq_finalize_kernel(const int* __restrict__ counts,
                                   const float* __restrict__ lossAcc,
                                   float* __restrict__ outTail) {
    __shared__ float red[256];
    const int tid = threadIdx.x;
    float perp = 0.f;
    for (int n = 0; n < N_G; ++n) {
        float h = 0.f;
        for (int m = tid; m < M_CB; m += 256) {
            const float p = (float)counts[n * M_CB + m] * (1.0f / (B_SZ * L_SEQ));
            h += p * logf(p + 1e-10f);
        }
        red[tid] = h;
        __syncthreads();
        #pragma unroll
        for (int s = 128; s > 0; s >>= 1) {
            if (tid < s) red[tid] += red[tid + s];
            __syncthreads();
        }
        if (tid == 0) perp += expf(-red[0]);
        __syncthreads();
    }
    if (tid == 0) {
        outTail[0] = 0.25f * (lossAcc[0] / (float)OUT_ELEMS);
        outTail[1] = perp;
    }
}

extern "C" void kernel_launch(void* const* d_in, const int* in_sizes, int n_in,
                              void* d_out, int out_size, void* d_ws, size_t ws_size,
                              hipStream_t stream) {
    const float* x   = (const float*)d_in[0];
    const float* emb = (const float*)d_in[1];
    float* out = (float*)d_out;
    char*  ws  = (char*)d_ws;

    if (ws_size >= WS_NEEDED) {
        unsigned int* ef16u  = (unsigned int*)(ws + EF_OFF);
        float* e2p    = (float*)(ws + E2P_OFF);
        float* e2r    = (float*)(ws + E2R_OFF);
        int*   counts = (int*)(ws + CNT_OFF);
        float* lossA  = (float*)(ws + LOSS_OFF);

        hipMemsetAsync(ws + CNT_OFF, 0, N_G * M_CB * 4 + 4, stream);
        vq_ef16_kernel<<<(N_G * M_CB * D_DIM / 2 + 255) / 256, 256, 0, stream>>>(emb, ef16u);
        vq_e2_kernel<<<(N_G * M_CB + 255) / 256, 256, 0, stream>>>(emb, e2r, e2p);
        vq_mfma_kernel<<<TOKENS / 256, 256, 0, stream>>>(
            x, emb, (const unsigned short*)ef16u, e2r, e2p, out, counts, lossA);
        vq_finalize_kernel<<<1, 256, 0, stream>>>(counts, lossA, out + OUT_ELEMS);
    } else {
        // fallback: validated R1 layout (e2 @0, counts @16K, loss @32K)
        float* e2tab  = (float*)ws;
        int*   counts = (int*)(ws + 16384);
        float* lossA  = (float*)(ws + 32768);
        hipMemsetAsync(ws + 16384, 0, 16384 + 4, stream);
        vq_e2_kernel<<<(N_G * M_CB + 255) / 256, 256, 0, stream>>>(emb, e2tab, nullptr);
        vq_main_fallback<<<TOKENS / 256, 256, 0, stream>>>(x, emb, e2tab, out, counts, lossA);
        vq_finalize_kernel<<<1, 256, 0, stream>>>(counts, lossA, out + OUT_ELEMS);
    }
}